// Round 11
// baseline (1140.319 us; speedup 1.0000x reference)
//
#include <hip/hip_runtime.h>
#include <hip/hip_bf16.h>

#define DD 768
#define NPATCH 576
#define NPAD 640          // 40 patch tiles of 16
#define NPT 40
#define BMR 64            // mem rows per chunk
#define GRID 256
#define EPSF 1e-6f

typedef short bf16x8 __attribute__((ext_vector_type(8)));
typedef float f32x4 __attribute__((ext_vector_type(4)));

__device__ __forceinline__ unsigned short f2bf(float x) {
  __hip_bfloat16 h = __float2bfloat16(x);
  return __builtin_bit_cast(unsigned short, h);
}

// ---------------- kernel 1: patch row norms ----------------
__global__ __launch_bounds__(256) void k_norm(const float* __restrict__ pf,
                                              float* __restrict__ invn) {
  int row = blockIdx.x;          // 576
  int t = threadIdx.x;
  const float* src = pf + (size_t)row * DD;
  float v0 = src[t], v1 = src[t + 256], v2 = src[t + 512];
  float ss = v0 * v0 + v1 * v1 + v2 * v2;
#pragma unroll
  for (int m = 1; m < 64; m <<= 1) ss += __shfl_xor(ss, m, 64);
  __shared__ float wss[4];
  if ((t & 63) == 0) wss[t >> 6] = ss;
  __syncthreads();
  if (t == 0) {
    float tot = wss[0] + wss[1] + wss[2] + wss[3];
    invn[row] = 1.0f / (sqrtf(tot) + EPSF);
  }
}

// ---------------- kernel 2: pack F into slab-fragment layout ----------------
// Fws[ks32][ptg][slot][8] bf16: patch = ptg*16+(slot&15), k = ks32*32+(slot>>4)*8+j
__global__ __launch_bounds__(256) void k_pack(const float* __restrict__ pf,
                                              const float* __restrict__ invn,
                                              unsigned short* __restrict__ Fws) {
  int bid = blockIdx.x;          // 960 = 24 ks * 40 ptg
  int ks = bid / NPT, ptg = bid % NPT;
  int t = threadIdx.x;
  int i = t * 2;                 // short index in region [0,512)
  int s = i >> 3, j = i & 7;
  int p = ptg * 16 + (s & 15);
  int k = ks * 32 + (s >> 4) * 8 + j;
  unsigned int outw = 0;
  if (p < NPATCH) {
    float sc = invn[p];
    float a0 = pf[(size_t)p * DD + k] * sc;
    float a1 = pf[(size_t)p * DD + k + 1] * sc;
    outw = (unsigned int)f2bf(a0) | ((unsigned int)f2bf(a1) << 16);
  }
  ((unsigned int*)Fws)[(size_t)bid * 256 + t] = outw;
}

#define PACK_BW(bw, u0, u1)                                               \
  bw.x = (unsigned int)f2bf(u0.x) | ((unsigned int)f2bf(u0.y) << 16);     \
  bw.y = (unsigned int)f2bf(u0.z) | ((unsigned int)f2bf(u0.w) << 16);     \
  bw.z = (unsigned int)f2bf(u1.x) | ((unsigned int)f2bf(u1.y) << 16);     \
  bw.w = (unsigned int)f2bf(u1.z) | ((unsigned int)f2bf(u1.w) << 16);

#define SQ8(u0, u1)                                                        \
  (u0.x * u0.x + u0.y * u0.y + u0.z * u0.z + u0.w * u0.w +                 \
   u1.x * u1.x + u1.y * u1.y + u1.z * u1.z + u1.w * u1.w)

// Issue the 12 float4 global loads for half hp of chunk cc (oldest in queue).
#define GLOAD(cc, hp)                                                       \
  {                                                                         \
    int grow_ = (cc) * BMR + crow;                                          \
    if (grow_ > M - 1) grow_ = M - 1;                                       \
    const float* gp_ = mem + (size_t)grow_ * DD + (hp) * 384 + gcol;        \
    _Pragma("unroll") for (int j = 0; j < 12; ++j)                          \
        fL[j] = *(const float4*)(gp_ + j * 4);                              \
  }

// Convert this thread's 48 floats -> 6 bf16x8 slots in BsB[hp] (swizzled),
// accumulating sum-of-squares once (not per wave!).
#define CONV(hp)                                                            \
  {                                                                         \
    _Pragma("unroll") for (int j = 0; j < 6; ++j) {                         \
      ssr += SQ8(fL[2 * j], fL[2 * j + 1]);                                 \
      uint4 bw_;                                                            \
      PACK_BW(bw_, fL[2 * j], fL[2 * j + 1]);                               \
      *(uint4*)(BsB[hp] + wb[j]) = bw_;                                     \
    }                                                                       \
  }

// One K=32 step (n = 0..23 literal). ARC holds A(n) (prefetched last step);
// prefetch A((n+1)%24) into ARN first (keeps gloads oldest). 4 bf16 ds_reads
// (conflict-free swizzle) + 20 MFMA. No VALU convert in the loop.
#define STEP(n, ARC, ARN)                                                    \
  {                                                                          \
    const unsigned short* An_ = Abase + (size_t)(((n) + 1) % 24) * (NPT * 512); \
    _Pragma("unroll") for (int p = 0; p < 5; ++p)                            \
        ARN[p] = *(const bf16x8*)(An_ + p * 512);                            \
    __builtin_amdgcn_sched_barrier(0);                                       \
    const char* bp_ = BsB[(n) / 12];                                         \
    int off_ = ((((n) % 12) * 4 + lhi) ^ fsw) << 4;                          \
    bf16x8 b0_ = *(const bf16x8*)(bp_ + dsb[0] + off_);                      \
    bf16x8 b1_ = *(const bf16x8*)(bp_ + dsb[1] + off_);                      \
    bf16x8 b2_ = *(const bf16x8*)(bp_ + dsb[2] + off_);                      \
    bf16x8 b3_ = *(const bf16x8*)(bp_ + dsb[3] + off_);                      \
    asm volatile("s_waitcnt lgkmcnt(0)" ::: "memory");                       \
    __builtin_amdgcn_sched_barrier(0);                                       \
    _Pragma("unroll") for (int p = 0; p < 5; ++p) {                          \
      acc[p][0] = __builtin_amdgcn_mfma_f32_16x16x32_bf16(ARC[p], b0_, acc[p][0], 0, 0, 0); \
      acc[p][1] = __builtin_amdgcn_mfma_f32_16x16x32_bf16(ARC[p], b1_, acc[p][1], 0, 0, 0); \
      acc[p][2] = __builtin_amdgcn_mfma_f32_16x16x32_bf16(ARC[p], b2_, acc[p][2], 0, 0, 0); \
      acc[p][3] = __builtin_amdgcn_mfma_f32_16x16x32_bf16(ARC[p], b3_, acc[p][3], 0, 0, 0); \
    }                                                                        \
    __builtin_amdgcn_sched_barrier(0);                                       \
  }

// ---------------- kernel 3: main MFMA kernel ----------------
// 512 threads = 8 waves; wave w owns patch tiles w*5..w*5+4 x all 4 row-tiles.
// One chunk (64 rows) per block iteration: B read ONCE from HBM, reg-staged,
// converted to bf16 ONCE into 2x48KB LDS half-chunk buffers. 3 raw barriers
// per chunk; counted vmcnt discipline (gloads oldest, A dbuf 1-step flight).
__global__ __launch_bounds__(512, 1) void k_main(const unsigned short* __restrict__ Fws,
                                                 const float* __restrict__ mem,
                                                 float* __restrict__ partial,
                                                 int M, int nchunk) {
  __shared__ __align__(16) char BsB[2][49152];   // 2 halves: 64 rows x 48 slots x 16B
  __shared__ float ssq[BMR];
  __shared__ float smin[NPAD];

  int t = threadIdx.x;
  int w = t >> 6, l = t & 63, l15 = l & 15, lhi = l >> 4;
  // conv/staging mapping: thread owns row crow, slots c8*6..c8*6+5 (16B each)
  int crow = t >> 3, c8 = t & 7;
  int csw = crow & 7;
  int gcol = c8 * 48;
  int wb[6];
#pragma unroll
  for (int j = 0; j < 6; ++j) wb[j] = crow * 768 + (((c8 * 6 + j) ^ csw) << 4);
  // fragment-read mapping: row rt*16+l15, slot ks*4+lhi, swizzle ^ (row&7)
  int fsw = l15 & 7;
  int dsb[4];
#pragma unroll
  for (int rt = 0; rt < 4; ++rt) dsb[rt] = (rt * 16 + l15) * 768;

  const unsigned short* Abase =
      Fws + (size_t)(w * 5) * 512 + (size_t)(lhi * 16 + l15) * 8;

  for (int i = t; i < NPAD; i += 512) smin[i] = 1e30f;
  __syncthreads();

  float4 fL[12];
  bf16x8 arE[5], arO[5];

  int chunk = blockIdx.x;
  GLOAD(chunk, 0);                 // oldest: B half-0 of first chunk
  {                                // prefetch A(0)
    const unsigned short* A0 = Abase;
#pragma unroll
    for (int p = 0; p < 5; ++p) arE[p] = *(const bf16x8*)(A0 + p * 512);
  }

#pragma unroll 1
  for (; chunk < nchunk; chunk += GRID) {
    f32x4 acc[5][4];
#pragma unroll
    for (int p = 0; p < 5; ++p)
#pragma unroll
      for (int rt = 0; rt < 4; ++rt) {
        f32x4 z = {0.f, 0.f, 0.f, 0.f};
        acc[p][rt] = z;
      }
    float ssr = 0.f;

    // ---- half 0: convert (waits its gloads via compiler vmcnt) ----
    CONV(0);
    asm volatile("s_waitcnt lgkmcnt(0)" ::: "memory");
    __builtin_amdgcn_sched_barrier(0);
    __builtin_amdgcn_s_barrier();
    GLOAD(chunk, 1);               // issue half-1 loads (oldest in queue now)
    STEP(0, arE, arO)  STEP(1, arO, arE)  STEP(2, arE, arO)  STEP(3, arO, arE)
    STEP(4, arE, arO)  STEP(5, arO, arE)  STEP(6, arE, arO)  STEP(7, arO, arE)
    STEP(8, arE, arO)  STEP(9, arO, arE)  STEP(10, arE, arO) STEP(11, arO, arE)

    // ---- half 1 ----
    CONV(1);
    asm volatile("s_waitcnt lgkmcnt(0)" ::: "memory");
    __builtin_amdgcn_sched_barrier(0);
    __builtin_amdgcn_s_barrier();
    {
      int cn = chunk + GRID;
      if (cn >= nchunk) cn = chunk;          // dummy reload (never consumed)
      GLOAD(cn, 0);                          // issue next chunk half-0 loads
    }
    STEP(12, arE, arO) STEP(13, arO, arE) STEP(14, arE, arO) STEP(15, arO, arE)
    STEP(16, arE, arO) STEP(17, arO, arE) STEP(18, arE, arO) STEP(19, arO, arE)
    STEP(20, arE, arO) STEP(21, arO, arE) STEP(22, arE, arO) STEP(23, arO, arE)

    // ---- ssq: each row's sum lives in 8 consecutive lanes ----
    {
      float v = ssr;
      v += __shfl_xor(v, 1, 64);
      v += __shfl_xor(v, 2, 64);
      v += __shfl_xor(v, 4, 64);
      if (c8 == 0) ssq[crow] = v;
    }
    asm volatile("s_waitcnt lgkmcnt(0)" ::: "memory");
    __builtin_amdgcn_sched_barrier(0);
    __builtin_amdgcn_s_barrier();

    // ---- epilogue: dist + per-patch min (rows clamped -> no okr needed) ----
    float inv_[4];
#pragma unroll
    for (int rt = 0; rt < 4; ++rt)
      inv_[rt] = 1.0f / (sqrtf(ssq[rt * 16 + l15]) + EPSF);
#pragma unroll
    for (int p = 0; p < 5; ++p) {
#pragma unroll
      for (int q = 0; q < 4; ++q) {
        float d = 1.0f - acc[p][0][q] * inv_[0];
        d = fminf(d, 1.0f - acc[p][1][q] * inv_[1]);
        d = fminf(d, 1.0f - acc[p][2][q] * inv_[2]);
        d = fminf(d, 1.0f - acc[p][3][q] * inv_[3]);
        d = fminf(d, __shfl_xor(d, 1, 64));
        d = fminf(d, __shfl_xor(d, 2, 64));
        d = fminf(d, __shfl_xor(d, 4, 64));
        d = fminf(d, __shfl_xor(d, 8, 64));
        if (l15 == 0) {
          int pl = (w * 5 + p) * 16 + lhi * 4 + q;
          smin[pl] = fminf(smin[pl], d);
        }
      }
    }
  }

  __syncthreads();
  for (int i = t; i < NPATCH; i += 512)
    partial[(size_t)blockIdx.x * NPAD + i] = smin[i];
}

// ---------------- kernel 4: min over partials -> patch_scores ----------------
__global__ __launch_bounds__(256) void k_colmin(const float* __restrict__ partial,
                                                float* __restrict__ out, int nb) {
  int p = blockIdx.x;   // 576
  int t = threadIdx.x;
  float v = 1e30f;
  for (int b = t; b < nb; b += 256) v = fminf(v, partial[(size_t)b * NPAD + p]);
#pragma unroll
  for (int m = 1; m < 64; m <<= 1) v = fminf(v, __shfl_xor(v, m, 64));
  __shared__ float wmin[4];
  if ((t & 63) == 0) wmin[t >> 6] = v;
  __syncthreads();
  if (t == 0) out[p] = fminf(fminf(wmin[0], wmin[1]), fminf(wmin[2], wmin[3]));
}

// ---------------- kernel 5: top-k mean -> image score ----------------
__global__ __launch_bounds__(256) void k_topk(float* __restrict__ out,
                                              const int* __restrict__ topk_p) {
  __shared__ float vals[NPATCH];
  __shared__ float wv[4];
  __shared__ int wi[4];
  __shared__ float ssum;
  int t = threadIdx.x;
  for (int p = t; p < NPATCH; p += 256) vals[p] = out[p];
  if (t == 0) ssum = 0.f;
  int k = topk_p[0];
  if (k > NPATCH) k = NPATCH;
  if (k < 1) k = 1;
  __syncthreads();
  for (int it = 0; it < k; ++it) {
    float bv = -1e30f;
    int bi = 0;
    for (int p = t; p < NPATCH; p += 256) {
      float x = vals[p];
      if (x > bv) { bv = x; bi = p; }
    }
#pragma unroll
    for (int m = 1; m < 64; m <<= 1) {
      float ov = __shfl_xor(bv, m, 64);
      int oi = __shfl_xor(bi, m, 64);
      if (ov > bv || (ov == bv && oi < bi)) { bv = ov; bi = oi; }
    }
    if ((t & 63) == 0) { wv[t >> 6] = bv; wi[t >> 6] = bi; }
    __syncthreads();
    if (t == 0) {
      float fbv = wv[0]; int fbi = wi[0];
      for (int q = 1; q < 4; ++q)
        if (wv[q] > fbv || (wv[q] == fbv && wi[q] < fbi)) { fbv = wv[q]; fbi = wi[q]; }
      ssum += fbv;
      vals[fbi] = -1e30f;
    }
    __syncthreads();
  }
  if (t == 0) out[NPATCH] = ssum / (float)k;
}

extern "C" void kernel_launch(void* const* d_in, const int* in_sizes, int n_in,
                              void* d_out, int out_size, void* d_ws, size_t ws_size,
                              hipStream_t stream) {
  const float* pf = (const float*)d_in[0];
  const float* mem = (const float*)d_in[1];
  const int* topk = (const int*)d_in[2];
  float* out = (float*)d_out;
  int M = in_sizes[1] / DD;                      // 200000
  int nchunk = (M + BMR - 1) / BMR;              // 3125

  // ws: Fws (24*40*512 shorts = 983040B) | invn (2560B) | partial (256*640*4)
  unsigned short* Fws = (unsigned short*)d_ws;
  float* invn = (float*)((char*)d_ws + 983040);
  float* partial = (float*)((char*)d_ws + 983040 + 2560);

  int grid = GRID;
  if (grid > nchunk) grid = nchunk;

  k_norm<<<NPATCH, 256, 0, stream>>>(pf, invn);
  k_pack<<<24 * NPT, 256, 0, stream>>>(pf, invn, Fws);
  k_main<<<grid, 512, 0, stream>>>(Fws, mem, partial, M, nchunk);
  k_colmin<<<NPATCH, 256, 0, stream>>>(partial, out, grid);
  k_topk<<<1, 256, 0, stream>>>(out, topk);
}

// Round 12
// 1073.666 us; speedup vs baseline: 1.0621x; 1.0621x over previous
//
#include <hip/hip_runtime.h>
#include <hip/hip_bf16.h>

#define DD 768
#define NPATCH 576
#define NPAD 640          // 40 patch tiles of 16
#define NPT 40
#define BMR 64            // mem rows per chunk
#define GRID 256
#define EPSF 1e-6f

typedef short bf16x8 __attribute__((ext_vector_type(8)));
typedef float f32x4 __attribute__((ext_vector_type(4)));

__device__ __forceinline__ unsigned short f2bf(float x) {
  __hip_bfloat16 h = __float2bfloat16(x);
  return __builtin_bit_cast(unsigned short, h);
}

__device__ __forceinline__ void gload_lds16(const float* g, char* lds) {
  __builtin_amdgcn_global_load_lds(
      (const __attribute__((address_space(1))) unsigned int*)(g),
      (__attribute__((address_space(3))) unsigned int*)(lds), 16, 0, 0);
}

// ---------------- kernel 1: patch row norms ----------------
__global__ __launch_bounds__(256) void k_norm(const float* __restrict__ pf,
                                              float* __restrict__ invn) {
  int row = blockIdx.x;          // 576
  int t = threadIdx.x;
  const float* src = pf + (size_t)row * DD;
  float v0 = src[t], v1 = src[t + 256], v2 = src[t + 512];
  float ss = v0 * v0 + v1 * v1 + v2 * v2;
#pragma unroll
  for (int m = 1; m < 64; m <<= 1) ss += __shfl_xor(ss, m, 64);
  __shared__ float wss[4];
  if ((t & 63) == 0) wss[t >> 6] = ss;
  __syncthreads();
  if (t == 0) {
    float tot = wss[0] + wss[1] + wss[2] + wss[3];
    invn[row] = 1.0f / (sqrtf(tot) + EPSF);
  }
}

// ---------------- kernel 2: pack F into slab-fragment layout ----------------
// Fws[ks32][ptg][slot][8] bf16: patch = ptg*16+(slot&15), k = ks32*32+(slot>>4)*8+j
__global__ __launch_bounds__(256) void k_pack(const float* __restrict__ pf,
                                              const float* __restrict__ invn,
                                              unsigned short* __restrict__ Fws) {
  int bid = blockIdx.x;          // 960 = 24 ks * 40 ptg
  int ks = bid / NPT, ptg = bid % NPT;
  int t = threadIdx.x;
  int i = t * 2;                 // short index in region [0,512)
  int s = i >> 3, j = i & 7;
  int p = ptg * 16 + (s & 15);
  int k = ks * 32 + (s >> 4) * 8 + j;
  unsigned int outw = 0;
  if (p < NPATCH) {
    float sc = invn[p];
    float a0 = pf[(size_t)p * DD + k] * sc;
    float a1 = pf[(size_t)p * DD + k + 1] * sc;
    outw = (unsigned int)f2bf(a0) | ((unsigned int)f2bf(a1) << 16);
  }
  ((unsigned int*)Fws)[(size_t)bid * 256 + t] = outw;
}

#define PACK_BW(bw, u0, u1)                                               \
  bw.x = (unsigned int)f2bf(u0.x) | ((unsigned int)f2bf(u0.y) << 16);     \
  bw.y = (unsigned int)f2bf(u0.z) | ((unsigned int)f2bf(u0.w) << 16);     \
  bw.z = (unsigned int)f2bf(u1.x) | ((unsigned int)f2bf(u1.y) << 16);     \
  bw.w = (unsigned int)f2bf(u1.z) | ((unsigned int)f2bf(u1.w) << 16);

#define SQ8(u0, u1)                                                        \
  (u0.x * u0.x + u0.y * u0.y + u0.z * u0.z + u0.w * u0.w +                 \
   u1.x * u1.x + u1.y * u1.y + u1.z * u1.z + u1.w * u1.w)

// Issue 15 A-fragment loads for k-slabs ks0..ks0+2 (kept OLDER than stage).
#define ALOAD(ks0)                                                         \
  { _Pragma("unroll") for (int s = 0; s < 3; ++s)                          \
      _Pragma("unroll") for (int p = 0; p < 5; ++p)                        \
        aR[s][p] = *(const bf16x8*)(Abase + (size_t)((ks0) + s) * (NPT * 512) + p * 512); \
    __builtin_amdgcn_sched_barrier(0); }

// Stage quarter qS (literal) of chunk cS into fpq[qS&1]: 6 gload_lds / wave,
// per-lane global source, linear LDS dest (rule #21 compliant).
#define STAGEQ(cS, qS)                                                     \
  { int cc_ = (cS);                                                        \
    _Pragma("unroll") for (int i = 0; i < 6; ++i) {                        \
      int gr_ = cc_ * BMR + srowL[i];                                      \
      if (gr_ > Mm1) gr_ = Mm1;                                            \
      gload_lds16((const float*)((const char*)mem + (size_t)gr_ * 3072 +   \
                                 (qS) * 768 + scolb[i]),                   \
                  (char*)fpq[(qS) & 1] + i * 8192 + w * 1024);             \
    }                                                                      \
    __builtin_amdgcn_sched_barrier(0); }

// Convert fpq[bi] (fp32, 48KB) -> bfq (bf16, 24KB, XOR-swizzled), once per
// quarter with work split across all 512 threads; ssq accumulated once.
#define CONVQ(bi)                                                          \
  { const char* fb_ = fpq[bi];                                             \
    _Pragma("unroll") for (int j = 0; j < 3; ++j) {                        \
      float4 u0 = *(const float4*)(fb_ + cvr + (2 * c8 + 16 * j) * 16);    \
      float4 u1 = *(const float4*)(fb_ + cvr + (2 * c8 + 16 * j) * 16 + 16); \
      ssr += SQ8(u0, u1);                                                  \
      uint4 bw_;                                                           \
      PACK_BW(bw_, u0, u1);                                                \
      *(uint4*)(bfq + cbw + wslb[j]) = bw_;                                \
    } }

// One K=32 MFMA step: 4 swizzled bf16 ds_read_b128 + 20 MFMA. No converts.
#define STEPQ(s, as)                                                       \
  { int off_ = (((s) * 4 + lhi) ^ fsw) << 4;                               \
    bf16x8 b0_ = *(const bf16x8*)(bfq + dsb0 + off_);                      \
    bf16x8 b1_ = *(const bf16x8*)(bfq + dsb1 + off_);                      \
    bf16x8 b2_ = *(const bf16x8*)(bfq + dsb2 + off_);                      \
    bf16x8 b3_ = *(const bf16x8*)(bfq + dsb3 + off_);                      \
    asm volatile("s_waitcnt lgkmcnt(0)" ::: "memory");                     \
    __builtin_amdgcn_sched_barrier(0);                                     \
    __builtin_amdgcn_s_setprio(1);                                         \
    _Pragma("unroll") for (int p = 0; p < 5; ++p) {                        \
      acc[p][0] = __builtin_amdgcn_mfma_f32_16x16x32_bf16(aR[as][p], b0_, acc[p][0], 0, 0, 0); \
      acc[p][1] = __builtin_amdgcn_mfma_f32_16x16x32_bf16(aR[as][p], b1_, acc[p][1], 0, 0, 0); \
      acc[p][2] = __builtin_amdgcn_mfma_f32_16x16x32_bf16(aR[as][p], b2_, acc[p][2], 0, 0, 0); \
      acc[p][3] = __builtin_amdgcn_mfma_f32_16x16x32_bf16(aR[as][p], b3_, acc[p][3], 0, 0, 0); \
    }                                                                      \
    __builtin_amdgcn_s_setprio(0);                                         \
    __builtin_amdgcn_sched_barrier(0);                                     \
  }

// Phase = one quarter: [A batch1 | stage next | drain stage(q) vmcnt(21) |
// barrier | convert-once | barrier | 3 steps | A batch2 | 3 steps]
#define PHASE(qq, cS, qS)                                                  \
  {                                                                        \
    ALOAD((qq) * 6)                                                        \
    STAGEQ(cS, qS)                                                         \
    asm volatile("s_waitcnt vmcnt(21)" ::: "memory");                      \
    __builtin_amdgcn_sched_barrier(0);                                     \
    __builtin_amdgcn_s_barrier();                                          \
    CONVQ((qq) & 1)                                                        \
    asm volatile("s_waitcnt lgkmcnt(0)" ::: "memory");                     \
    __builtin_amdgcn_sched_barrier(0);                                     \
    __builtin_amdgcn_s_barrier();                                          \
    STEPQ(0, 0) STEPQ(1, 1) STEPQ(2, 2)                                    \
    ALOAD((qq) * 6 + 3)                                                    \
    STEPQ(3, 0) STEPQ(4, 1) STEPQ(5, 2)                                    \
  }

// ---------------- kernel 3: main MFMA kernel ----------------
// 512 threads = 8 waves; wave w owns patch tiles w*5..w*5+4 x all 4 row-tiles.
// One chunk (64 rows) per block iteration: B read ONCE from HBM via
// global_load_lds (fp32), converted to bf16 ONCE per quarter by all threads.
__global__ __launch_bounds__(512, 1) void k_main(const unsigned short* __restrict__ Fws,
                                                 const float* __restrict__ mem,
                                                 float* __restrict__ partial,
                                                 int M, int nchunk) {
  __shared__ __align__(16) char fpq[2][49152];  // fp32 quarters (DMA dest)
  __shared__ __align__(16) char bfq[24576];     // bf16 quarter (converted)
  __shared__ float ssq[BMR];
  __shared__ float smin[NPAD];

  int t = threadIdx.x;
  int w = t >> 6, l = t & 63, l15 = l & 15, lhi = l >> 4;
  int Mm1 = M - 1;

  // staging decode: dest flat16 = i*512 + t -> (row, slot); linear both sides
  int srowL[6], scolb[6];
#pragma unroll
  for (int i = 0; i < 6; ++i) {
    int flat = i * 512 + t;
    int r = flat / 48;
    srowL[i] = r;
    scolb[i] = (flat - r * 48) * 16;
  }
  // convert mapping: thread owns row crow, fp32 slot pairs {2c8+16j, +1}
  int crow = t >> 3, c8 = t & 7;
  int cvr = crow * 768, cbw = crow * 384, csw = crow & 7;
  int wslb[3];
#pragma unroll
  for (int j = 0; j < 3; ++j) wslb[j] = ((c8 + 8 * j) ^ csw) << 4;
  // fragment-read mapping: row rt*16+l15, slot (s*4+lhi)^(row&7)
  int fsw = l15 & 7;
  int dsb0 = (0 * 16 + l15) * 384;
  int dsb1 = (1 * 16 + l15) * 384;
  int dsb2 = (2 * 16 + l15) * 384;
  int dsb3 = (3 * 16 + l15) * 384;

  const unsigned short* Abase =
      Fws + (size_t)(w * 5) * 512 + (size_t)(lhi * 16 + l15) * 8;

  for (int i = t; i < NPAD; i += 512) smin[i] = 1e30f;
  // (no barrier needed: PHASE(0)'s barriers precede first smin use)

  bf16x8 aR[3][5];
  f32x4 acc[5][4];

  int chunk = blockIdx.x;
  STAGEQ(chunk, 0)               // prologue: quarter 0 in flight

#pragma unroll 1
  for (; chunk < nchunk; chunk += GRID) {
    int cnx = chunk + GRID;
    if (cnx >= nchunk) cnx = chunk;      // dummy re-stage (never consumed)

#pragma unroll
    for (int p = 0; p < 5; ++p)
#pragma unroll
      for (int rt = 0; rt < 4; ++rt) {
        f32x4 z = {0.f, 0.f, 0.f, 0.f};
        acc[p][rt] = z;
      }
    float ssr = 0.f;

    PHASE(0, chunk, 1)
    PHASE(1, chunk, 2)
    PHASE(2, chunk, 3)
    PHASE(3, cnx, 0)

    // ---- ssq: row sum lives in 8 consecutive lanes (c8) ----
    {
      float v = ssr;
      v += __shfl_xor(v, 1, 64);
      v += __shfl_xor(v, 2, 64);
      v += __shfl_xor(v, 4, 64);
      if (c8 == 0) ssq[crow] = v;
    }
    asm volatile("s_waitcnt lgkmcnt(0)" ::: "memory");
    __builtin_amdgcn_sched_barrier(0);
    __builtin_amdgcn_s_barrier();

    // ---- epilogue: dist + per-patch min ----
    float inv0 = 1.0f / (sqrtf(ssq[l15]) + EPSF);
    float inv1 = 1.0f / (sqrtf(ssq[16 + l15]) + EPSF);
    float inv2 = 1.0f / (sqrtf(ssq[32 + l15]) + EPSF);
    float inv3 = 1.0f / (sqrtf(ssq[48 + l15]) + EPSF);
#pragma unroll
    for (int p = 0; p < 5; ++p) {
#pragma unroll
      for (int q = 0; q < 4; ++q) {
        float d = 1.0f - acc[p][0][q] * inv0;
        d = fminf(d, 1.0f - acc[p][1][q] * inv1);
        d = fminf(d, 1.0f - acc[p][2][q] * inv2);
        d = fminf(d, 1.0f - acc[p][3][q] * inv3);
        d = fminf(d, __shfl_xor(d, 1, 64));
        d = fminf(d, __shfl_xor(d, 2, 64));
        d = fminf(d, __shfl_xor(d, 4, 64));
        d = fminf(d, __shfl_xor(d, 8, 64));
        if (l15 == 0) {
          int pl = (w * 5 + p) * 16 + lhi * 4 + q;
          smin[pl] = fminf(smin[pl], d);
        }
      }
    }
  }

  __syncthreads();
  for (int i = t; i < NPATCH; i += 512)
    partial[(size_t)blockIdx.x * NPAD + i] = smin[i];
}

// ---------------- kernel 4: min over partials -> patch_scores ----------------
__global__ __launch_bounds__(256) void k_colmin(const float* __restrict__ partial,
                                                float* __restrict__ out, int nb) {
  int p = blockIdx.x;   // 576
  int t = threadIdx.x;
  float v = 1e30f;
  for (int b = t; b < nb; b += 256) v = fminf(v, partial[(size_t)b * NPAD + p]);
#pragma unroll
  for (int m = 1; m < 64; m <<= 1) v = fminf(v, __shfl_xor(v, m, 64));
  __shared__ float wmin[4];
  if ((t & 63) == 0) wmin[t >> 6] = v;
  __syncthreads();
  if (t == 0) out[p] = fminf(fminf(wmin[0], wmin[1]), fminf(wmin[2], wmin[3]));
}

// ---------------- kernel 5: top-k mean -> image score ----------------
__global__ __launch_bounds__(256) void k_topk(float* __restrict__ out,
                                              const int* __restrict__ topk_p) {
  __shared__ float vals[NPATCH];
  __shared__ float wv[4];
  __shared__ int wi[4];
  __shared__ float ssum;
  int t = threadIdx.x;
  for (int p = t; p < NPATCH; p += 256) vals[p] = out[p];
  if (t == 0) ssum = 0.f;
  int k = topk_p[0];
  if (k > NPATCH) k = NPATCH;
  if (k < 1) k = 1;
  __syncthreads();
  for (int it = 0; it < k; ++it) {
    float bv = -1e30f;
    int bi = 0;
    for (int p = t; p < NPATCH; p += 256) {
      float x = vals[p];
      if (x > bv) { bv = x; bi = p; }
    }
#pragma unroll
    for (int m = 1; m < 64; m <<= 1) {
      float ov = __shfl_xor(bv, m, 64);
      int oi = __shfl_xor(bi, m, 64);
      if (ov > bv || (ov == bv && oi < bi)) { bv = ov; bi = oi; }
    }
    if ((t & 63) == 0) { wv[t >> 6] = bv; wi[t >> 6] = bi; }
    __syncthreads();
    if (t == 0) {
      float fbv = wv[0]; int fbi = wi[0];
      for (int q = 1; q < 4; ++q)
        if (wv[q] > fbv || (wv[q] == fbv && wi[q] < fbi)) { fbv = wv[q]; fbi = wi[q]; }
      ssum += fbv;
      vals[fbi] = -1e30f;
    }
    __syncthreads();
  }
  if (t == 0) out[NPATCH] = ssum / (float)k;
}

extern "C" void kernel_launch(void* const* d_in, const int* in_sizes, int n_in,
                              void* d_out, int out_size, void* d_ws, size_t ws_size,
                              hipStream_t stream) {
  const float* pf = (const float*)d_in[0];
  const float* mem = (const float*)d_in[1];
  const int* topk = (const int*)d_in[2];
  float* out = (float*)d_out;
  int M = in_sizes[1] / DD;                      // 200000
  int nchunk = (M + BMR - 1) / BMR;              // 3125

  // ws: Fws (24*40*512 shorts = 983040B) | invn (2560B) | partial (256*640*4)
  unsigned short* Fws = (unsigned short*)d_ws;
  float* invn = (float*)((char*)d_ws + 983040);
  float* partial = (float*)((char*)d_ws + 983040 + 2560);

  int grid = GRID;
  if (grid > nchunk) grid = nchunk;

  k_norm<<<NPATCH, 256, 0, stream>>>(pf, invn);
  k_pack<<<24 * NPT, 256, 0, stream>>>(pf, invn, Fws);
  k_main<<<grid, 512, 0, stream>>>(Fws, mem, partial, M, nchunk);
  k_colmin<<<NPATCH, 256, 0, stream>>>(partial, out, grid);
  k_topk<<<1, 256, 0, stream>>>(out, topk);
}

// Round 13
// 660.283 us; speedup vs baseline: 1.7270x; 1.6261x over previous
//
#include <hip/hip_runtime.h>
#include <hip/hip_bf16.h>

#define DD 768
#define NPATCH 576
#define NPAD 640          // 40 patch tiles of 16
#define NPT 40
#define BMR 64            // mem rows per chunk
#define GRID 512          // 2 blocks/CU; each chunk owned by ONE block
#define EPSF 1e-6f

typedef short bf16x8 __attribute__((ext_vector_type(8)));
typedef float f32x4 __attribute__((ext_vector_type(4)));

__device__ __forceinline__ unsigned short f2bf(float x) {
  __hip_bfloat16 h = __float2bfloat16(x);
  return __builtin_bit_cast(unsigned short, h);
}

__device__ __forceinline__ void gload_lds16(const float* g, char* lds) {
  __builtin_amdgcn_global_load_lds(
      (const __attribute__((address_space(1))) unsigned int*)(g),
      (__attribute__((address_space(3))) unsigned int*)(lds), 16, 0, 0);
}

// ---------------- kernel 1: patch row norms ----------------
__global__ __launch_bounds__(256) void k_norm(const float* __restrict__ pf,
                                              float* __restrict__ invn) {
  int row = blockIdx.x;          // 576
  int t = threadIdx.x;
  const float* src = pf + (size_t)row * DD;
  float v0 = src[t], v1 = src[t + 256], v2 = src[t + 512];
  float ss = v0 * v0 + v1 * v1 + v2 * v2;
#pragma unroll
  for (int m = 1; m < 64; m <<= 1) ss += __shfl_xor(ss, m, 64);
  __shared__ float wss[4];
  if ((t & 63) == 0) wss[t >> 6] = ss;
  __syncthreads();
  if (t == 0) {
    float tot = wss[0] + wss[1] + wss[2] + wss[3];
    invn[row] = 1.0f / (sqrtf(tot) + EPSF);
  }
}

// ---------------- kernel 2: pack F into slab-fragment layout ----------------
// Fws[ks32][ptg][slot][8] bf16: patch = ptg*16+(slot&15), k = ks32*32+(slot>>4)*8+j
__global__ __launch_bounds__(256) void k_pack(const float* __restrict__ pf,
                                              const float* __restrict__ invn,
                                              unsigned short* __restrict__ Fws) {
  int bid = blockIdx.x;          // 960 = 24 ks * 40 ptg
  int ks = bid / NPT, ptg = bid % NPT;
  int t = threadIdx.x;
  int i = t * 2;                 // short index in region [0,512)
  int s = i >> 3, j = i & 7;
  int p = ptg * 16 + (s & 15);
  int k = ks * 32 + (s >> 4) * 8 + j;
  unsigned int outw = 0;
  if (p < NPATCH) {
    float sc = invn[p];
    float a0 = pf[(size_t)p * DD + k] * sc;
    float a1 = pf[(size_t)p * DD + k + 1] * sc;
    outw = (unsigned int)f2bf(a0) | ((unsigned int)f2bf(a1) << 16);
  }
  ((unsigned int*)Fws)[(size_t)bid * 256 + t] = outw;
}

#define PACK_BW(bw, u0, u1)                                               \
  bw.x = (unsigned int)f2bf(u0.x) | ((unsigned int)f2bf(u0.y) << 16);     \
  bw.y = (unsigned int)f2bf(u0.z) | ((unsigned int)f2bf(u0.w) << 16);     \
  bw.z = (unsigned int)f2bf(u1.x) | ((unsigned int)f2bf(u1.y) << 16);     \
  bw.w = (unsigned int)f2bf(u1.z) | ((unsigned int)f2bf(u1.w) << 16);

#define SQ8(u0, u1)                                                        \
  (u0.x * u0.x + u0.y * u0.y + u0.z * u0.z + u0.w * u0.w +                 \
   u1.x * u1.x + u1.y * u1.y + u1.z * u1.z + u1.w * u1.w)

// Stage phase qp (literal 0..11, 64 floats/row) of chunk cc into fpq[qp&1].
// Linear LDS dest (wave-uniform base; HW adds lane*16); per-lane pre-swizzled
// global source so conv reads are bank-balanced (rule #21: both sides).
#define STAGEQ(cc, qp)                                                     \
  { int cc_ = (cc);                                                        \
    _Pragma("unroll") for (int i = 0; i < 2; ++i) {                        \
      int gr_ = cc_ * BMR + srowL[i];                                      \
      if (gr_ > Mm1) gr_ = Mm1;                                            \
      gload_lds16((const float*)((const char*)mem + (size_t)gr_ * 3072 +   \
                                 (qp) * 256 + scolx[i]),                   \
                  (char*)fpq[(qp) & 1] + i * 8192 + w * 1024);             \
    }                                                                      \
    __builtin_amdgcn_sched_barrier(0); }

// Issue both A-slab fragment batches for phase p (10 global b128, L2-hot).
#define ALOAD2(p)                                                          \
  { const unsigned short* A0_ = Abase + (size_t)(2 * (p)) * (NPT * 512);   \
    const unsigned short* A1_ = A0_ + (NPT * 512);                         \
    _Pragma("unroll") for (int pp = 0; pp < 5; ++pp)                       \
        aX[pp] = *(const bf16x8*)(A0_ + pp * 512);                         \
    _Pragma("unroll") for (int pp = 0; pp < 5; ++pp)                       \
        aY[pp] = *(const bf16x8*)(A1_ + pp * 512);                         \
    __builtin_amdgcn_sched_barrier(0); }

// Convert-once: this thread's 8 floats of fpq[p&1] -> 1 bf16 slot in bfB.
#define CONVP(p)                                                           \
  { const char* fb_ = fpq[(p) & 1];                                        \
    float4 f0_ = *(const float4*)(fb_ + cv0);                              \
    float4 f1_ = *(const float4*)(fb_ + cv1);                              \
    ssr += SQ8(f0_, f1_);                                                  \
    uint4 bw_;                                                             \
    PACK_BW(bw_, f0_, f1_);                                                \
    *(uint4*)(bfB + bwo) = bw_;                                            \
    __builtin_amdgcn_sched_barrier(0); }

// One K=32 step: 4 swizzled bf16 ds_read_b128 + 20 MFMA. Zero VALU converts.
#define STEPP(sofj, AR)                                                    \
  { bf16x8 b0_ = *(const bf16x8*)(bfB + dsb[0] + sofj);                    \
    bf16x8 b1_ = *(const bf16x8*)(bfB + dsb[1] + sofj);                    \
    bf16x8 b2_ = *(const bf16x8*)(bfB + dsb[2] + sofj);                    \
    bf16x8 b3_ = *(const bf16x8*)(bfB + dsb[3] + sofj);                    \
    asm volatile("s_waitcnt lgkmcnt(0)" ::: "memory");                     \
    __builtin_amdgcn_sched_barrier(0);                                     \
    __builtin_amdgcn_s_setprio(1);                                         \
    _Pragma("unroll") for (int pp = 0; pp < 5; ++pp) {                     \
      acc[pp][0] = __builtin_amdgcn_mfma_f32_16x16x32_bf16(AR[pp], b0_, acc[pp][0], 0, 0, 0); \
      acc[pp][1] = __builtin_amdgcn_mfma_f32_16x16x32_bf16(AR[pp], b1_, acc[pp][1], 0, 0, 0); \
      acc[pp][2] = __builtin_amdgcn_mfma_f32_16x16x32_bf16(AR[pp], b2_, acc[pp][2], 0, 0, 0); \
      acc[pp][3] = __builtin_amdgcn_mfma_f32_16x16x32_bf16(AR[pp], b3_, acc[pp][3], 0, 0, 0); \
    }                                                                      \
    __builtin_amdgcn_s_setprio(0);                                         \
    __builtin_amdgcn_sched_barrier(0); }

// Phase: [vmcnt(0) drains G | barrier | A issue | conv | lgkm barrier |
//         STEP0 (A-wait vmcnt(5)) | stage G(next) | STEP1 (A-wait vmcnt(2))]
#define PHASE(p, gc)                                                       \
  {                                                                        \
    asm volatile("s_waitcnt vmcnt(0) lgkmcnt(0)" ::: "memory");            \
    __builtin_amdgcn_sched_barrier(0);                                     \
    __builtin_amdgcn_s_barrier();                                          \
    __builtin_amdgcn_sched_barrier(0);                                     \
    ALOAD2(p)                                                              \
    CONVP(p)                                                               \
    asm volatile("s_waitcnt lgkmcnt(0)" ::: "memory");                     \
    __builtin_amdgcn_sched_barrier(0);                                     \
    __builtin_amdgcn_s_barrier();                                          \
    __builtin_amdgcn_sched_barrier(0);                                     \
    STEPP(soff0, aX)                                                       \
    STAGEQ(gc, ((p) + 1) % 12)                                             \
    STEPP(soff1, aY)                                                       \
  }

// ---------------- kernel 3: main MFMA kernel ----------------
// 512 threads = 8 waves; wave w owns patch tiles w*5..w*5+4 x all 4 row-tiles.
// One chunk per block iteration (B read once). 12 phases x 2 slabs; fp32
// staged by global_load_lds, converted to bf16 ONCE per phase by all threads.
__global__ __launch_bounds__(512, 2) void k_main(const unsigned short* __restrict__ Fws,
                                                 const float* __restrict__ mem,
                                                 float* __restrict__ partial,
                                                 int M, int nchunk) {
  __shared__ __align__(16) char fpq[2][16384];  // fp32 phase buffers (DMA dest)
  __shared__ __align__(16) char bfB[8192];      // bf16 phase buffer (converted)
  __shared__ float ssq[BMR];
  __shared__ float smin[NPAD];

  int t = threadIdx.x;
  int w = t >> 6, l = t & 63, l15 = l & 15, lhi = l >> 4;
  int Mm1 = M - 1;

  // staging decode: dest 16B-slot p16 = i*512+t -> (row=p16>>4, colS=p16&15);
  // source col = swz(colS) so that conv's swizzled reads see logical order
  int srowL[2], scolx[2];
#pragma unroll
  for (int i = 0; i < 2; ++i) {
    int p16 = i * 512 + t;
    int r = p16 >> 4, cs = p16 & 15;
    srowL[i] = r;
    scolx[i] = (((cs ^ (r & 7)) & 7) | (cs & 8)) << 4;
  }
  // convert decode: thread owns row crow=t>>3, logical 16B-cols {2c8, 2c8+1}
  int crow = t >> 3, c8 = t & 7, cr7 = crow & 7;
  int cv0 = crow * 256 + (((((2 * c8) ^ cr7) & 7) | ((2 * c8) & 8)) << 4);
  int cv1 = crow * 256 + (((((2 * c8 + 1) ^ cr7) & 7) | ((2 * c8 + 1) & 8)) << 4);
  int bwo = crow * 128 + ((c8 ^ cr7) << 4);    // bf16 slot c8, XOR-swizzled
  // fragment decode: row rt*16+l15, slot j*4+lhi, phys = slot ^ (row&7)
  int fsw = l15 & 7;
  int dsb[4];
#pragma unroll
  for (int rt = 0; rt < 4; ++rt) dsb[rt] = (rt * 16 + l15) * 128;
  int soff0 = ((lhi ^ fsw) & 7) << 4;
  int soff1 = (((4 + lhi) ^ fsw) & 7) << 4;

  const unsigned short* Abase =
      Fws + (size_t)(w * 5) * 512 + (size_t)(lhi * 16 + l15) * 8;

  for (int i = t; i < NPAD; i += 512) smin[i] = 1e30f;

  bf16x8 aX[5], aY[5];
  f32x4 acc[5][4];

  int chunk = blockIdx.x;
  STAGEQ(chunk, 0)               // prologue: phase 0 in flight

#pragma unroll 1
  for (; chunk < nchunk; chunk += GRID) {
    int cnx = chunk + GRID;
    if (cnx >= nchunk) cnx = chunk;      // dummy re-stage (never consumed)

#pragma unroll
    for (int pp = 0; pp < 5; ++pp)
#pragma unroll
      for (int rt = 0; rt < 4; ++rt) {
        f32x4 z = {0.f, 0.f, 0.f, 0.f};
        acc[pp][rt] = z;
      }
    float ssr = 0.f;

    PHASE(0, chunk)  PHASE(1, chunk)  PHASE(2, chunk)  PHASE(3, chunk)
    PHASE(4, chunk)  PHASE(5, chunk)  PHASE(6, chunk)  PHASE(7, chunk)
    PHASE(8, chunk)  PHASE(9, chunk)  PHASE(10, chunk) PHASE(11, cnx)

    // ---- ssq: row sum lives in 8 consecutive lanes (c8) ----
    {
      float v = ssr;
      v += __shfl_xor(v, 1, 64);
      v += __shfl_xor(v, 2, 64);
      v += __shfl_xor(v, 4, 64);
      if (c8 == 0) ssq[crow] = v;
    }
    asm volatile("s_waitcnt lgkmcnt(0)" ::: "memory");
    __builtin_amdgcn_sched_barrier(0);
    __builtin_amdgcn_s_barrier();

    // ---- epilogue: dist + per-patch min (rows clamped; padded patches d=1) ----
    float inv0 = 1.0f / (sqrtf(ssq[l15]) + EPSF);
    float inv1 = 1.0f / (sqrtf(ssq[16 + l15]) + EPSF);
    float inv2 = 1.0f / (sqrtf(ssq[32 + l15]) + EPSF);
    float inv3 = 1.0f / (sqrtf(ssq[48 + l15]) + EPSF);
#pragma unroll
    for (int pp = 0; pp < 5; ++pp) {
#pragma unroll
      for (int q = 0; q < 4; ++q) {
        float d = 1.0f - acc[pp][0][q] * inv0;
        d = fminf(d, 1.0f - acc[pp][1][q] * inv1);
        d = fminf(d, 1.0f - acc[pp][2][q] * inv2);
        d = fminf(d, 1.0f - acc[pp][3][q] * inv3);
        d = fminf(d, __shfl_xor(d, 1, 64));
        d = fminf(d, __shfl_xor(d, 2, 64));
        d = fminf(d, __shfl_xor(d, 4, 64));
        d = fminf(d, __shfl_xor(d, 8, 64));
        if (l15 == 0) {
          int pl = (w * 5 + pp) * 16 + lhi * 4 + q;
          smin[pl] = fminf(smin[pl], d);
        }
      }
    }
  }

  __syncthreads();
  for (int i = t; i < NPATCH; i += 512)
    partial[(size_t)blockIdx.x * NPAD + i] = smin[i];
}

// ---------------- kernel 4: min over partials -> patch_scores ----------------
__global__ __launch_bounds__(256) void k_colmin(const float* __restrict__ partial,
                                                float* __restrict__ out, int nb) {
  int p = blockIdx.x;   // 576
  int t = threadIdx.x;
  float v = 1e30f;
  for (int b = t; b < nb; b += 256) v = fminf(v, partial[(size_t)b * NPAD + p]);
#pragma unroll
  for (int m = 1; m < 64; m <<= 1) v = fminf(v, __shfl_xor(v, m, 64));
  __shared__ float wmin[4];
  if ((t & 63) == 0) wmin[t >> 6] = v;
  __syncthreads();
  if (t == 0) out[p] = fminf(fminf(wmin[0], wmin[1]), fminf(wmin[2], wmin[3]));
}

// ---------------- kernel 5: top-k mean -> image score ----------------
__global__ __launch_bounds__(256) void k_topk(float* __restrict__ out,
                                              const int* __restrict__ topk_p) {
  __shared__ float vals[NPATCH];
  __shared__ float wv[4];
  __shared__ int wi[4];
  __shared__ float ssum;
  int t = threadIdx.x;
  for (int p = t; p < NPATCH; p += 256) vals[p] = out[p];
  if (t == 0) ssum = 0.f;
  int k = topk_p[0];
  if (k > NPATCH) k = NPATCH;
  if (k < 1) k = 1;
  __syncthreads();
  for (int it = 0; it < k; ++it) {
    float bv = -1e30f;
    int bi = 0;
    for (int p = t; p < NPATCH; p += 256) {
      float x = vals[p];
      if (x > bv) { bv = x; bi = p; }
    }
#pragma unroll
    for (int m = 1; m < 64; m <<= 1) {
      float ov = __shfl_xor(bv, m, 64);
      int oi = __shfl_xor(bi, m, 64);
      if (ov > bv || (ov == bv && oi < bi)) { bv = ov; bi = oi; }
    }
    if ((t & 63) == 0) { wv[t >> 6] = bv; wi[t >> 6] = bi; }
    __syncthreads();
    if (t == 0) {
      float fbv = wv[0]; int fbi = wi[0];
      for (int q = 1; q < 4; ++q)
        if (wv[q] > fbv || (wv[q] == fbv && wi[q] < fbi)) { fbv = wv[q]; fbi = wi[q]; }
      ssum += fbv;
      vals[fbi] = -1e30f;
    }
    __syncthreads();
  }
  if (t == 0) out[NPATCH] = ssum / (float)k;
}

extern "C" void kernel_launch(void* const* d_in, const int* in_sizes, int n_in,
                              void* d_out, int out_size, void* d_ws, size_t ws_size,
                              hipStream_t stream) {
  const float* pf = (const float*)d_in[0];
  const float* mem = (const float*)d_in[1];
  const int* topk = (const int*)d_in[2];
  float* out = (float*)d_out;
  int M = in_sizes[1] / DD;                      // 200000
  int nchunk = (M + BMR - 1) / BMR;              // 3125

  // ws: Fws (24*40*512 shorts = 983040B) | invn (2560B) | partial (512*640*4)
  unsigned short* Fws = (unsigned short*)d_ws;
  float* invn = (float*)((char*)d_ws + 983040);
  float* partial = (float*)((char*)d_ws + 983040 + 2560);

  int grid = GRID;
  if (grid > nchunk) grid = nchunk;

  k_norm<<<NPATCH, 256, 0, stream>>>(pf, invn);
  k_pack<<<24 * NPT, 256, 0, stream>>>(pf, invn, Fws);
  k_main<<<grid, 512, 0, stream>>>(Fws, mem, partial, M, nchunk);
  k_colmin<<<NPATCH, 256, 0, stream>>>(partial, out, grid);
  k_topk<<<1, 256, 0, stream>>>(out, topk);
}